// Round 1
// 1876.639 us; speedup vs baseline: 1.0684x; 1.0684x over previous
//
#include <hip/hip_runtime.h>
#include <hip/hip_bf16.h>
#include <cstdint>

// Layouts:
//   Y1 (bf16, N x 640):  [ q(128: h*64+d) | t(256: h*128+f) | k(128) | m(128) ]
//   Xagg (f32, N x 384): [ magg(128) | s_h0(128) | s_h1(128) ]  (unnormalized)
//   W1t_hi/lo (bf16, 640 x 128): TRANSPOSED projection weights (rows = out col q|t|k|m)
//   W2t_hi/lo (bf16, 64 x 640):  TRANSPOSED output weights
// GEMMs run on MFMA (16x16x32 bf16) with split-bf16 3-term compensation
// (AhBh + AhBl + AlBh) so accuracy stays fp32-class.
// Edge grouping: counting sort by dst -> off[N+1], elist[E]. One wave per node
// accumulates in registers; zero global atomics on the hot path.

typedef __attribute__((ext_vector_type(8))) short bf16x8;
typedef __attribute__((ext_vector_type(4))) float f32x4;

__device__ __forceinline__ unsigned short f2bf(float x) {
    unsigned int u = __float_as_uint(x);
    u += 0x7FFFu + ((u >> 16) & 1u);   // round-to-nearest-even
    return (unsigned short)(u >> 16);
}
__device__ __forceinline__ float bflo(unsigned int u) { return __uint_as_float(u << 16); }
__device__ __forceinline__ float bfhi(unsigned int u) { return __uint_as_float(u & 0xFFFF0000u); }

__device__ __forceinline__ void splitbf(float x, unsigned short& h, unsigned short& l) {
    unsigned short hh = f2bf(x);
    float rem = x - __uint_as_float((unsigned int)hh << 16);
    h = hh;
    l = f2bf(rem);
}

__global__ void zero_f4(float4* __restrict__ p, long n4) {
    long i = (long)blockIdx.x * blockDim.x + threadIdx.x;
    long stride = (long)gridDim.x * blockDim.x;
    float4 z = make_float4(0.f, 0.f, 0.f, 0.f);
    for (; i < n4; i += stride) p[i] = z;
}

// Build W1^T split into bf16 hi/lo: W1t[c][f], c in [0,640), f in [0,128)
__global__ void build_w1(const float* __restrict__ wm, const float* __restrict__ wq,
                         const float* __restrict__ wk,
                         unsigned short* __restrict__ W1tH,
                         unsigned short* __restrict__ W1tL) {
    int idx = blockIdx.x * blockDim.x + threadIdx.x;
    if (idx >= 128 * 640) return;
    int f = idx / 640, c = idx % 640;
    float v;
    if (c < 128) {                       // q
        int h = c >> 6, dd = c & 63;
        v = wq[h * 8192 + f * 64 + dd];
    } else if (c < 384) {                // t:  A[h,f,f2] = sum_d wq[h,f,d]*wm[h,f2,d]
        int cc = c - 128, h = cc >> 7, f2 = cc & 127;
        float s = 0.f;
        for (int dd = 0; dd < 64; ++dd)
            s += wq[h * 8192 + f * 64 + dd] * wm[h * 8192 + f2 * 64 + dd];
        v = s;
    } else if (c < 512) {                // k
        int cc = c - 384, h = cc >> 6, dd = cc & 63;
        v = wk[h * 8192 + f * 64 + dd];
    } else {                             // m
        int cc = c - 512, h = cc >> 6, dd = cc & 63;
        v = wm[h * 8192 + f * 64 + dd];
    }
    unsigned short h16, l16;
    splitbf(v, h16, l16);
    W1tH[(size_t)c * 128 + f] = h16;
    W1tL[(size_t)c * 128 + f] = l16;
}

// Build W2^T split into bf16 hi/lo: W2t[j][rr], j in [0,64), rr in [0,640)
__global__ void build_w2(const float* __restrict__ wm, const float* __restrict__ whe,
                         const float* __restrict__ whd,
                         unsigned short* __restrict__ W2tH,
                         unsigned short* __restrict__ W2tL) {
    int idx = blockIdx.x * blockDim.x + threadIdx.x;
    if (idx >= 640 * 64) return;
    int rr = idx / 64, j = idx % 64;
    float v;
    if (rr < 128) {                      // magg path: w_h_entity rows (h*64+d)
        v = whe[rr * 64 + j];
    } else if (rr < 384) {               // s path: P_h[f2,j] = sum_d wm[h,f2,d]*whe[h*64+d, j]
        int cc = rr - 128, h = cc >> 7, f2 = cc & 127;
        float s = 0.f;
        for (int dd = 0; dd < 64; ++dd)
            s += wm[h * 8192 + f2 * 64 + dd] * whe[(h * 64 + dd) * 64 + j];
        v = s;
    } else {                             // dialogue path
        v = whd[(rr - 384) * 64 + j];
    }
    unsigned short h16, l16;
    splitbf(v, h16, l16);
    W2tH[(size_t)j * 640 + rr] = h16;
    W2tL[(size_t)j * 640 + rr] = l16;
}

// Y1 = entity_features (M x 128) @ W1 (128 x 640), stored bf16.
// MFMA split-bf16. Tile 128x128, K=128 in one LDS load, 4 waves each 64x64.
__global__ __launch_bounds__(256) void gemm_proj_mfma(
        const float* __restrict__ F,
        const unsigned short* __restrict__ W1tH, const unsigned short* __restrict__ W1tL,
        unsigned short* __restrict__ Y1, int M) {
    // +8 element row pad -> 2-way max bank aliasing on ds_read_b128 (free)
    __shared__ unsigned short AH[128 * 136];
    __shared__ unsigned short AL[128 * 136];
    __shared__ unsigned short BH[128 * 136];
    __shared__ unsigned short BL[128 * 136];
    int m0 = blockIdx.x * 128;
    int n0 = blockIdx.y * 128;
    int tid = threadIdx.x;

    // stage A: 128 rows x 128 k, f32 -> split bf16 (2 threads/row, 64 cols each)
    {
        int row = tid >> 1, seg = tid & 1;
        int gr = m0 + row;
        const float* src = F + (size_t)gr * 128 + seg * 64;
        unsigned short* dh = AH + row * 136 + seg * 64;
        unsigned short* dl = AL + row * 136 + seg * 64;
        #pragma unroll
        for (int v = 0; v < 16; ++v) {
            float4 x = make_float4(0.f, 0.f, 0.f, 0.f);
            if (gr < M) x = *(const float4*)(src + v * 4);
            ushort4 h4, l4;
            splitbf(x.x, h4.x, l4.x);
            splitbf(x.y, h4.y, l4.y);
            splitbf(x.z, h4.z, l4.z);
            splitbf(x.w, h4.w, l4.w);
            *(ushort4*)(dh + v * 4) = h4;
            *(ushort4*)(dl + v * 4) = l4;
        }
    }
    // stage B: 128 n-rows x 128 k, already split bf16 in global (plain copy)
    {
        int row = tid >> 1, seg = tid & 1;
        const unsigned short* sh = W1tH + (size_t)(n0 + row) * 128 + seg * 64;
        const unsigned short* sl = W1tL + (size_t)(n0 + row) * 128 + seg * 64;
        unsigned short* dh = BH + row * 136 + seg * 64;
        unsigned short* dl = BL + row * 136 + seg * 64;
        #pragma unroll
        for (int v = 0; v < 8; ++v) {
            *(uint4*)(dh + v * 8) = *(const uint4*)(sh + v * 8);
            *(uint4*)(dl + v * 8) = *(const uint4*)(sl + v * 8);
        }
    }
    __syncthreads();

    int l = tid & 63, wid = tid >> 6;
    int wr = (wid >> 1) * 64, wc = (wid & 1) * 64;
    int r16 = l & 15, k8 = (l >> 4) * 8;
    f32x4 acc[4][4] = {};
    #pragma unroll
    for (int kc = 0; kc < 4; ++kc) {
        int ko = kc * 32 + k8;
        bf16x8 ah[4], al[4], bh[4], bl[4];
        #pragma unroll
        for (int i = 0; i < 4; ++i) {
            ah[i] = *(const bf16x8*)(AH + (wr + i * 16 + r16) * 136 + ko);
            al[i] = *(const bf16x8*)(AL + (wr + i * 16 + r16) * 136 + ko);
            bh[i] = *(const bf16x8*)(BH + (wc + i * 16 + r16) * 136 + ko);
            bl[i] = *(const bf16x8*)(BL + (wc + i * 16 + r16) * 136 + ko);
        }
        #pragma unroll
        for (int i = 0; i < 4; ++i) {
            #pragma unroll
            for (int j = 0; j < 4; ++j) {
                acc[i][j] = __builtin_amdgcn_mfma_f32_16x16x32_bf16(ah[i], bh[j], acc[i][j], 0, 0, 0);
                acc[i][j] = __builtin_amdgcn_mfma_f32_16x16x32_bf16(ah[i], bl[j], acc[i][j], 0, 0, 0);
                acc[i][j] = __builtin_amdgcn_mfma_f32_16x16x32_bf16(al[i], bh[j], acc[i][j], 0, 0, 0);
            }
        }
    }
    // C/D layout: col = lane&15, row = (lane>>4)*4 + reg
    int g4 = (l >> 4) * 4, c16 = l & 15;
    #pragma unroll
    for (int i = 0; i < 4; ++i) {
        #pragma unroll
        for (int r = 0; r < 4; ++r) {
            int gr = m0 + wr + i * 16 + g4 + r;
            if (gr < M) {
                #pragma unroll
                for (int j = 0; j < 4; ++j)
                    Y1[(size_t)gr * 640 + n0 + wc + j * 16 + c16] = f2bf(acc[i][j][r]);
            }
        }
    }
}

// ---- counting sort of edges by dst ----
__global__ void hist_dst(const int* __restrict__ dst, int* __restrict__ cnt, int E) {
    int e = blockIdx.x * blockDim.x + threadIdx.x;
    if (e < E) atomicAdd(&cnt[dst[e]], 1);
}

__global__ void scan_pass1(const int* __restrict__ cnt, int* __restrict__ bsum, int N) {
    __shared__ int sd[256];
    int i = blockIdx.x * 256 + threadIdx.x;
    sd[threadIdx.x] = (i < N) ? cnt[i] : 0;
    __syncthreads();
    for (int s = 128; s > 0; s >>= 1) {
        if (threadIdx.x < s) sd[threadIdx.x] += sd[threadIdx.x + s];
        __syncthreads();
    }
    if (threadIdx.x == 0) bsum[blockIdx.x] = sd[0];
}

__global__ void scan_pass2(int* __restrict__ bsum, int nb) {
    __shared__ int sd[1024];
    int t = threadIdx.x;
    int v = (t < nb) ? bsum[t] : 0;
    sd[t] = v;
    __syncthreads();
    for (int o = 1; o < 1024; o <<= 1) {
        int x = (t >= o) ? sd[t - o] : 0;
        __syncthreads();
        sd[t] += x;
        __syncthreads();
    }
    if (t < nb) bsum[t] = sd[t] - v;   // exclusive
}

__global__ void scan_pass3(const int* __restrict__ cnt, const int* __restrict__ bsum,
                           int* __restrict__ off, int* __restrict__ cursor, int N, int E) {
    __shared__ int sd[256];
    int t = threadIdx.x;
    int i = blockIdx.x * 256 + t;
    int v = (i < N) ? cnt[i] : 0;
    sd[t] = v;
    __syncthreads();
    for (int o = 1; o < 256; o <<= 1) {
        int x = (t >= o) ? sd[t - o] : 0;
        __syncthreads();
        sd[t] += x;
        __syncthreads();
    }
    int excl = sd[t] - v + bsum[blockIdx.x];
    if (i < N) { off[i] = excl; cursor[i] = excl; }
    if (i == N - 1) off[N] = E;
}

__global__ void scatter_edges(const int* __restrict__ dst, int* __restrict__ cursor,
                              int* __restrict__ elist, int E) {
    int e = blockIdx.x * blockDim.x + threadIdx.x;
    if (e < E) {
        int p = atomicAdd(&cursor[dst[e]], 1);
        elist[p] = e;
    }
}

// One wave per node: loop incoming edges, accumulate in registers, store once.
__global__ __launch_bounds__(256) void node_gather(
        const float* __restrict__ R, const int* __restrict__ srcArr,
        const int* __restrict__ off, const int* __restrict__ elist,
        const unsigned short* __restrict__ Y1,
        float* __restrict__ Xagg, float* __restrict__ denom, int N) {
    int n = blockIdx.x * 4 + (threadIdx.x >> 6);
    if (n >= N) return;
    int l = threadIdx.x & 63;
    const unsigned int* yd = (const unsigned int*)(Y1 + (size_t)n * 640);
    unsigned int qu = yd[l], t0u = yd[64 + l], t1u = yd[128 + l];
    float qx = bflo(qu),  qy = bfhi(qu);
    float t0x = bflo(t0u), t0y = bfhi(t0u);
    float t1x = bflo(t1u), t1y = bfhi(t1u);
    int e0 = off[n], e1 = off[n + 1];
    float maccx = 0.f, maccy = 0.f;
    float s0x = 0.f, s0y = 0.f, s1x = 0.f, s1y = 0.f;
    float den0 = 0.f, den1 = 0.f;
    for (int e = e0; e < e1; ++e) {
        int eid = elist[e];
        int sI = srcArr[eid];
        const unsigned int* ys = (const unsigned int*)(Y1 + (size_t)sI * 640);
        unsigned int ku = ys[192 + l];
        unsigned int mu = ys[256 + l];
        float2 rv = *(const float2*)(R + (size_t)eid * 128 + 2 * l);
        float kx = bflo(ku), ky = bfhi(ku);
        float mx = bflo(mu), my = bfhi(mu);
        float kqp = kx * qx + ky * qy;           // head = l>>5
        float a0 = rv.x * t0x + rv.y * t0y;      // r . t[dst,h0]
        float a1 = rv.x * t1x + rv.y * t1y;      // r . t[dst,h1]
        if (l < 32) a0 += kqp; else a1 += kqp;
        #pragma unroll
        for (int o = 32; o; o >>= 1) {
            a0 += __shfl_xor(a0, o);
            a1 += __shfl_xor(a1, o);
        }
        a0 = (a0 >= 0.f) ? a0 : 0.01f * a0;      // LeakyReLU(0.01)
        a1 = (a1 >= 0.f) ? a1 : 0.01f * a1;
        float p0 = __expf(a0), p1 = __expf(a1);  // scores bounded, fp32-safe
        float w = (l < 32) ? p0 : p1;
        maccx += w * mx;  maccy += w * my;
        s0x += p0 * rv.x; s0y += p0 * rv.y;
        s1x += p1 * rv.x; s1y += p1 * rv.y;
        den0 += p0; den1 += p1;
    }
    float* xd = Xagg + (size_t)n * 384;
    *(float2*)(xd + 2 * l)       = make_float2(maccx, maccy);
    *(float2*)(xd + 128 + 2 * l) = make_float2(s0x, s0y);
    *(float2*)(xd + 256 + 2 * l) = make_float2(s1x, s1y);
    if (l == 0) {
        denom[(size_t)n * 2]     = den0;
        denom[(size_t)n * 2 + 1] = den1;
    }
}

// out = [Xagg/denom | dial] (M x 640) @ W2 (640 x 64), MFMA split-bf16.
// Tile 128x64, K=640 in 5 chunks of 128; 4 waves each 64x32.
__global__ __launch_bounds__(256) void gemm_out_mfma(
        const float* __restrict__ Xagg, const float* __restrict__ denom,
        const float* __restrict__ dial,
        const unsigned short* __restrict__ W2tH, const unsigned short* __restrict__ W2tL,
        float* __restrict__ out, int M) {
    __shared__ unsigned short XH[128 * 136];
    __shared__ unsigned short XL[128 * 136];
    __shared__ unsigned short WH[64 * 136];
    __shared__ unsigned short WL[64 * 136];
    int m0 = blockIdx.x * 128;
    int tid = threadIdx.x;
    int l = tid & 63, wid = tid >> 6;
    int wr = (wid >> 1) * 64, wc = (wid & 1) * 32;
    int r16 = l & 15, k8 = (l >> 4) * 8;
    f32x4 acc[4][2] = {};

    int row = tid >> 1, seg = tid & 1;
    int gr = m0 + row;
    float sc0 = 0.f, sc1 = 0.f;
    if (gr < M) {
        float d0 = denom[(size_t)gr * 2], d1 = denom[(size_t)gr * 2 + 1];
        sc0 = (d0 > 0.f) ? 1.f / d0 : 0.f;
        sc1 = (d1 > 0.f) ? 1.f / d1 : 0.f;
    }

    for (int kc = 0; kc < 5; ++kc) {
        // stage X chunk: cols [kc*128, kc*128+128), normalize + split
        {
            int c0 = kc * 128 + seg * 64;
            unsigned short* dh = XH + row * 136 + seg * 64;
            unsigned short* dl = XL + row * 136 + seg * 64;
            #pragma unroll
            for (int v = 0; v < 16; ++v) {
                int cc = c0 + v * 4;
                float4 x = make_float4(0.f, 0.f, 0.f, 0.f);
                if (gr < M) {
                    if (cc < 384) {
                        x = *(const float4*)(Xagg + (size_t)gr * 384 + cc);
                        float s = (cc < 128) ? ((cc & 64) ? sc1 : sc0)
                                             : ((cc < 256) ? sc0 : sc1);
                        x.x *= s; x.y *= s; x.z *= s; x.w *= s;
                    } else {
                        x = *(const float4*)(dial + (size_t)gr * 256 + (cc - 384));
                    }
                }
                ushort4 h4, l4;
                splitbf(x.x, h4.x, l4.x);
                splitbf(x.y, h4.y, l4.y);
                splitbf(x.z, h4.z, l4.z);
                splitbf(x.w, h4.w, l4.w);
                *(ushort4*)(dh + v * 4) = h4;
                *(ushort4*)(dl + v * 4) = l4;
            }
        }
        // stage W chunk: 64 n-rows x 128 k (plain copy of pre-split bf16)
        {
            int n = tid >> 2, s4 = tid & 3;
            const unsigned short* sh = W2tH + (size_t)n * 640 + kc * 128 + s4 * 32;
            const unsigned short* sl = W2tL + (size_t)n * 640 + kc * 128 + s4 * 32;
            unsigned short* dh = WH + n * 136 + s4 * 32;
            unsigned short* dl = WL + n * 136 + s4 * 32;
            #pragma unroll
            for (int v = 0; v < 4; ++v) {
                *(uint4*)(dh + v * 8) = *(const uint4*)(sh + v * 8);
                *(uint4*)(dl + v * 8) = *(const uint4*)(sl + v * 8);
            }
        }
        __syncthreads();
        #pragma unroll
        for (int k2 = 0; k2 < 4; ++k2) {
            int ko = k2 * 32 + k8;
            bf16x8 ah[4], al[4], bh[2], bl[2];
            #pragma unroll
            for (int i = 0; i < 4; ++i) {
                ah[i] = *(const bf16x8*)(XH + (wr + i * 16 + r16) * 136 + ko);
                al[i] = *(const bf16x8*)(XL + (wr + i * 16 + r16) * 136 + ko);
            }
            #pragma unroll
            for (int j = 0; j < 2; ++j) {
                bh[j] = *(const bf16x8*)(WH + (wc + j * 16 + r16) * 136 + ko);
                bl[j] = *(const bf16x8*)(WL + (wc + j * 16 + r16) * 136 + ko);
            }
            #pragma unroll
            for (int i = 0; i < 4; ++i) {
                #pragma unroll
                for (int j = 0; j < 2; ++j) {
                    acc[i][j] = __builtin_amdgcn_mfma_f32_16x16x32_bf16(ah[i], bh[j], acc[i][j], 0, 0, 0);
                    acc[i][j] = __builtin_amdgcn_mfma_f32_16x16x32_bf16(ah[i], bl[j], acc[i][j], 0, 0, 0);
                    acc[i][j] = __builtin_amdgcn_mfma_f32_16x16x32_bf16(al[i], bh[j], acc[i][j], 0, 0, 0);
                }
            }
        }
        __syncthreads();
    }
    int g4 = (l >> 4) * 4, c16 = l & 15;
    #pragma unroll
    for (int i = 0; i < 4; ++i) {
        #pragma unroll
        for (int r = 0; r < 4; ++r) {
            int gr2 = m0 + wr + i * 16 + g4 + r;
            if (gr2 < M) {
                #pragma unroll
                for (int j = 0; j < 2; ++j)
                    out[(size_t)gr2 * 64 + wc + j * 16 + c16] = acc[i][j][r];
            }
        }
    }
}

extern "C" void kernel_launch(void* const* d_in, const int* in_sizes, int n_in,
                              void* d_out, int out_size, void* d_ws, size_t ws_size,
                              hipStream_t stream) {
    const float* entity = (const float*)d_in[0];
    const float* rel    = (const float*)d_in[1];
    const float* dial   = (const float*)d_in[2];
    const float* wm     = (const float*)d_in[3];
    const float* wq     = (const float*)d_in[4];
    const float* wk     = (const float*)d_in[5];
    const float* whe    = (const float*)d_in[6];
    const float* whd    = (const float*)d_in[7];
    const int*   src    = (const int*)d_in[8];
    const int*   dst    = (const int*)d_in[9];
    int N = in_sizes[0] / 128;
    int E = in_sizes[8];
    float* out = (float*)d_out;

    // workspace layout (all segments 16B-aligned)
    float* ws    = (float*)d_ws;
    float* Xagg  = ws;                                   // N*384 f32
    float* denom = Xagg + (size_t)N * 384;               // N*2 f32
    unsigned short* Y1   = (unsigned short*)(denom + (size_t)N * 2); // N*640 bf16
    unsigned short* W1tH = Y1 + (size_t)N * 640;         // 640*128
    unsigned short* W1tL = W1tH + 640 * 128;             // 640*128
    unsigned short* W2tH = W1tL + 640 * 128;             // 64*640
    unsigned short* W2tL = W2tH + 64 * 640;              // 64*640
    int* ip      = (int*)(W2tL + 64 * 640);
    int* cnt     = ip;                                   // N
    int* offp    = cnt + N;                              // N+1
    int* cursor  = offp + N + 1;                         // N
    int* elist   = cursor + N;                           // E
    int* bsum    = elist + E;                            // up to 1024

    int nb = (N + 255) / 256;                            // scan blocks (<=1024)

    zero_f4<<<256, 256, 0, stream>>>((float4*)cnt, (long)N / 4);
    build_w1<<<(128 * 640 + 255) / 256, 256, 0, stream>>>(wm, wq, wk, W1tH, W1tL);
    build_w2<<<(640 * 64 + 255) / 256, 256, 0, stream>>>(wm, whe, whd, W2tH, W2tL);
    dim3 g1((N + 127) / 128, 5);
    gemm_proj_mfma<<<g1, 256, 0, stream>>>(entity, W1tH, W1tL, Y1, N);
    hist_dst<<<(E + 255) / 256, 256, 0, stream>>>(dst, cnt, E);
    scan_pass1<<<nb, 256, 0, stream>>>(cnt, bsum, N);
    scan_pass2<<<1, 1024, 0, stream>>>(bsum, nb);
    scan_pass3<<<nb, 256, 0, stream>>>(cnt, bsum, offp, cursor, N, E);
    scatter_edges<<<(E + 255) / 256, 256, 0, stream>>>(dst, cursor, elist, E);
    node_gather<<<(N + 3) / 4, 256, 0, stream>>>(rel, src, offp, elist, Y1, Xagg, denom, N);
    gemm_out_mfma<<<(N + 127) / 128, 256, 0, stream>>>(Xagg, denom, dial, W2tH, W2tL, out, N);
}